// Round 9
// baseline (184.699 us; speedup 1.0000x reference)
//
#include <hip/hip_runtime.h>

#define NEGINF (-1e30f)

// ---------------- problem constants ----------------
// b=4, c=64, h=w=5, q=75, u=100, N_WAY=5, K_SHOT=5
// M_s = 125 (per way), M_u = 2500, M_q = 25, M_tot = 2625
// ---------------- workspace layout (float units) ----------------
constexpr size_t OF_UNL  = 0;                              // [4][2500][64]
constexpr size_t OF_SUP  = OF_UNL  + (size_t)4*2500*64;    // [4][5][125][64]
constexpr size_t OF_SUPT = OF_SUP  + (size_t)4*5*125*64;   // [4][5][64][128]
constexpr size_t OF_QT   = OF_SUPT + (size_t)4*5*64*128;   // [300][25][64]  TRANSPOSED (mq-major)
constexpr size_t OF_ROWV = OF_QT   + (size_t)300*64*25;    // [4][5][8ck][2500] f
constexpr size_t OF_ROWI = OF_ROWV + (size_t)4*5*8*2500;   // [4][5][8ck][2500] i
constexpr size_t OF_CVI  = OF_ROWI + (size_t)4*5*8*2500;   // [4][5][125][20][2]
constexpr size_t OF_CMP  = OF_CVI  + (size_t)4*5*125*20*2; // [4][5][2500] i
constexpr size_t OF_CNT  = OF_CMP  + (size_t)4*5*2500;     // [20] i
constexpr size_t OF_UNEAR= OF_CNT  + 20;                   // [4][2500] i
constexpr size_t OF_SNEAR= OF_UNEAR+ 10000;                // [4][625]  i
constexpr size_t OF_BV   = OF_SNEAR+ 2500;                 // [300][5][25] f
constexpr size_t OF_BP   = OF_BV   + 37500;                // [300][5][25] i
constexpr size_t OF_AMX  = OF_BP   + 37500;                // [300][3200] u8

// ============================================================
// Kernel A: L2-normalize all three tensors into ws layouts.
// Query now written [bq][mq][64] (stride-1 -> coalesced) for kc1's
// LDS staging.
// ============================================================
__global__ __launch_bounds__(256) void knorm(
    const float* __restrict__ sup, const float* __restrict__ qry,
    const float* __restrict__ unl,
    float* __restrict__ unl_n, float* __restrict__ sup_n,
    float* __restrict__ supT, float* __restrict__ qt)
{
    int gid = blockIdx.x * 256 + threadIdx.x;
    int loc = gid >> 4;
    int sub = gid & 15;
    if (loc >= 20000) return;

    const float* src;
    float* dst1;
    float* dst2 = nullptr;

    if (loc < 10000) {
        int b = loc / 2500, m = loc % 2500;
        int u = m / 25, hw = m % 25;
        src  = unl + ((size_t)(b*100 + u) * 64) * 25 + hw;
        dst1 = unl_n + (size_t)loc * 64;
    } else if (loc < 12500) {
        int idx = loc - 10000;
        int b = idx / 625, r = idx % 625;
        int w = r / 125,  n = r % 125;
        int shot = n / 25, hw = n % 25;
        src  = sup + ((size_t)(b*25 + w*5 + shot) * 64) * 25 + hw;
        dst1 = sup_n + (size_t)idx * 64;
        dst2 = supT + ((size_t)(b*5 + w) * 64) * 128 + n;
    } else {
        int idx = loc - 12500;
        int bq = idx / 25, mq = idx % 25;
        src  = qry + ((size_t)bq * 64) * 25 + mq;
        dst1 = qt + ((size_t)bq * 25 + mq) * 64;   // [bq][mq][c]
    }

    float v[4]; float ss = 0.f;
    int c0 = sub * 4;
#pragma unroll
    for (int j = 0; j < 4; ++j) { v[j] = src[(size_t)(c0 + j) * 25]; ss += v[j] * v[j]; }
#pragma unroll
    for (int msk = 1; msk < 16; msk <<= 1) ss += __shfl_xor(ss, msk);
    float sc = 1.f / fmaxf(sqrtf(ss), 1e-12f);
#pragma unroll
    for (int j = 0; j < 4; ++j) {
        float o = v[j] * sc;
        dst1[c0 + j] = o;
        if (dst2) dst2[(size_t)(c0 + j) * 128] = o;
    }
}

// ============================================================
// Kernel B: u2s pass. 1600 blocks x 256 threads.
// (unchanged from round 8 — LDS-staged sup tile, broadcast reads)
// ============================================================
__global__ __launch_bounds__(256) void kb(
    const float* __restrict__ unl_n, const float* __restrict__ supT,
    float* __restrict__ rowv, int* __restrict__ rowi, float* __restrict__ colvi)
{
    int bid = blockIdx.x;
    int nc = bid & 3;
    int mb = (bid >> 2) % 20;
    int bw = bid / 80;               // b*5+w
    int b  = bw / 5;
    int tid = threadIdx.x;
    int lane = tid & 63, wv = tid >> 6;

    __shared__ float uls[128 * 65];
    __shared__ float sls[64 * 36];
    __shared__ float sv_[4][32];
    __shared__ int   si_[4][32];

    int m0 = mb * 128;
    int n0 = nc * 32;

    for (int i = tid; i < 128 * 16; i += 256) {
        int row = i >> 4, c4 = (i & 15) * 4;
        int m = m0 + row;
        float4 x = make_float4(0.f, 0.f, 0.f, 0.f);
        if (m < 2500) x = *(const float4*)(unl_n + ((size_t)(b * 2500 + m)) * 64 + c4);
        uls[row * 65 + c4 + 0] = x.x;
        uls[row * 65 + c4 + 1] = x.y;
        uls[row * 65 + c4 + 2] = x.z;
        uls[row * 65 + c4 + 3] = x.w;
    }
    {
        int c = tid >> 2, q = tid & 3;
        const float* sp = supT + ((size_t)bw * 64 + c) * 128 + n0 + q * 8;
        float4 a = *(const float4*)sp;
        float4 d4 = *(const float4*)(sp + 4);
        float* d = &sls[c * 36 + q * 8];
        d[0] = a.x; d[1] = a.y; d[2] = a.z; d[3] = a.w;
        d[4] = d4.x; d[5] = d4.y; d[6] = d4.z; d[7] = d4.w;
    }
    __syncthreads();

    int ml = tid & 127;
    int m  = m0 + ml;
    int nh = tid >> 7;
    int nbase = nh * 16;
    int nn_total = (125 - n0) < 32 ? (125 - n0) : 32;
    const float* myrow = &uls[ml * 65];

    float acc[16];
#pragma unroll
    for (int j = 0; j < 16; ++j) acc[j] = 0.f;

    for (int c = 0; c < 64; ++c) {
        float uv = myrow[c];
        const float4* sr = (const float4*)&sls[c * 36 + nbase];
        float4 s0 = sr[0], s1 = sr[1], s2 = sr[2], s3 = sr[3];
        acc[0]  = fmaf(uv, s0.x, acc[0]);  acc[1]  = fmaf(uv, s0.y, acc[1]);
        acc[2]  = fmaf(uv, s0.z, acc[2]);  acc[3]  = fmaf(uv, s0.w, acc[3]);
        acc[4]  = fmaf(uv, s1.x, acc[4]);  acc[5]  = fmaf(uv, s1.y, acc[5]);
        acc[6]  = fmaf(uv, s1.z, acc[6]);  acc[7]  = fmaf(uv, s1.w, acc[7]);
        acc[8]  = fmaf(uv, s2.x, acc[8]);  acc[9]  = fmaf(uv, s2.y, acc[9]);
        acc[10] = fmaf(uv, s2.z, acc[10]); acc[11] = fmaf(uv, s2.w, acc[11]);
        acc[12] = fmaf(uv, s3.x, acc[12]); acc[13] = fmaf(uv, s3.y, acc[13]);
        acc[14] = fmaf(uv, s3.z, acc[14]); acc[15] = fmaf(uv, s3.w, acc[15]);
    }

    int nnloc = nn_total - nbase;
    nnloc = nnloc < 0 ? 0 : (nnloc > 16 ? 16 : nnloc);
    float rbv = NEGINF; int rbi = 0;
    for (int j = 0; j < nnloc; ++j)
        if (acc[j] > rbv) { rbv = acc[j]; rbi = n0 + nbase + j; }
    if (m < 2500) {
        int ck = nc * 2 + nh;
        rowv[((size_t)bw * 8 + ck) * 2500 + m] = rbv;
        rowi[((size_t)bw * 8 + ck) * 2500 + m] = rbi;
    }

#pragma unroll
    for (int j = 0; j < 16; ++j) {
        float v = (m < 2500 && (nbase + j) < nn_total) ? acc[j] : NEGINF;
        float vm = v;
#pragma unroll
        for (int s2 = 1; s2 < 64; s2 <<= 1) vm = fmaxf(vm, __shfl_xor(vm, s2));
        unsigned long long msk = __ballot(v == vm);
        int first = __ffsll((unsigned long long)msk) - 1;
        if (lane == 0) { sv_[wv][nbase + j] = vm; si_[wv][nbase + j] = m0 + (wv & 1) * 64 + first; }
    }
    __syncthreads();
    if (tid < nn_total) {
        int w0 = (tid < 16) ? 0 : 2;
        float v = sv_[w0][tid];     int vi = si_[w0][tid];
        float v2 = sv_[w0 + 1][tid]; int i2 = si_[w0 + 1][tid];
        if (v2 > v || (v2 == v && i2 < vi)) { v = v2; vi = i2; }
        float* cv = colvi + ((((size_t)bw) * 125 + (n0 + tid)) * 20 + mb) * 2;
        cv[0] = v; ((int*)cv)[1] = vi;
    }
}

// ============================================================
// Kernel M: merge row partials -> unear, col partials -> snear.
// ============================================================
__global__ __launch_bounds__(256) void kmerge(
    const float* __restrict__ rowv, const int* __restrict__ rowi,
    const float* __restrict__ colvi,
    int* __restrict__ unear, int* __restrict__ snear)
{
    int it = blockIdx.x * 256 + threadIdx.x;
    if (it < 10000) {
        int b = it / 2500, m = it % 2500;
        float bv = NEGINF; int bi = 0;
#pragma unroll
        for (int w = 0; w < 5; ++w) {
#pragma unroll
            for (int ck = 0; ck < 8; ++ck) {
                size_t o = (((size_t)(b * 5 + w)) * 8 + ck) * 2500 + m;
                float v = rowv[o];
                if (v > bv) { bv = v; bi = w * 125 + rowi[o]; }
            }
        }
        unear[it] = bi;
    } else if (it < 12500) {
        int idx = it - 10000;
        const float* p = colvi + (size_t)idx * 40;
        float bv = NEGINF; int bi = 0x7fffffff;
        for (int mb2 = 0; mb2 < 20; ++mb2) {
            float v = p[mb2 * 2]; int vi = ((const int*)p)[mb2 * 2 + 1];
            if (v > bv || (v == bv && vi < bi)) { bv = v; bi = vi; }
        }
        snear[idx] = bi;
    }
}

// ============================================================
// Kernel P: mutual-NN mask + stable stream compaction. 20 blocks x 256.
// ============================================================
__global__ __launch_bounds__(256) void kcmp(
    const int* __restrict__ unear, const int* __restrict__ snear,
    int* __restrict__ cmp, int* __restrict__ cntg)
{
    int p = blockIdx.x;
    int b = p / 5, way = p % 5;
    int tid = threadIdx.x, lane = tid & 63, wv = tid >> 6;
    __shared__ unsigned long long masks[40];
    __shared__ int base[40];

    for (int ch = wv; ch < 40; ch += 4) {
        int m = ch * 64 + lane;
        bool ok = false;
        if (m < 2500) {
            int un = unear[b * 2500 + m];
            ok = (un / 125 == way) && (snear[b * 625 + un] == m);
        }
        unsigned long long msk = __ballot(ok ? 1 : 0);
        if (lane == 0) masks[ch] = msk;
    }
    __syncthreads();
    if (tid == 0) {
        int s = 0;
        for (int ch = 0; ch < 40; ++ch) { base[ch] = s; s += __popcll(masks[ch]); }
        cntg[p] = s;
    }
    __syncthreads();
    for (int ch = wv; ch < 40; ch += 4) {
        unsigned long long msk = masks[ch];
        if ((msk >> lane) & 1ull) {
            int pre = __popcll(msk & ((1ull << lane) - 1ull));
            cmp[(size_t)p * 2500 + base[ch] + pre] = ch * 64 + lane;
        }
    }
}

// ============================================================
// Kernel C1: query similarity, one block (256 thr) per (bq, way).
// Round-8 fix (same as kb's): q tile (25x64 = 6.4 KB) staged in LDS,
// inner loop reads q via WAVE-UNIFORM ds_read_b128 (HW broadcast) —
// per-lane VMEM re-loads of block-uniform q addresses were the 44 us
// bottleneck (compiler does NOT scalar-promote them; proven in kb r7).
// Per wave-column: 1600 FMA + 400 uniform b128 + 16 global b128.
// cnt_w <= 125 structurally -> cw <= 250 -> chunk loop runs once.
// ============================================================
__global__ __launch_bounds__(256) void kc1(
    const float* __restrict__ qt, const float* __restrict__ sup_n,
    const float* __restrict__ unl_n, const int* __restrict__ cmp,
    const int* __restrict__ cntg,
    float* __restrict__ bvg, int* __restrict__ bpg,
    unsigned char* __restrict__ amaxg)
{
    int bid = blockIdx.x;
    int w = bid % 5, bq = bid / 5;
    int b = bq / 75;
    int tid = threadIdx.x;

    const float* qtb = qt + (size_t)bq * 1600;   // [mq][c]

    int L = 0;
#pragma unroll
    for (int i = 0; i < 20; ++i) { int v = cntg[i]; L = L > v ? L : v; }
    int cntw = 0, wb = 0;
#pragma unroll
    for (int w2 = 0; w2 < 5; ++w2) {
        int c2 = cntg[b * 5 + w2];
        if (w2 < w) wb += 125 + c2;
        if (w2 == w) cntw = c2;
    }
    int cw = 125 + cntw;

    __shared__ float qls[25 * 64];     // [mq][c]
    __shared__ float simb[25 * 257];
    __shared__ float redv[8][25];
    __shared__ int   redp[8][25];

    // stage q tile: 1600 contiguous floats, coalesced
    for (int i = tid; i < 1600; i += 256) qls[i] = qtb[i];

    int rg = tid / 25, rq = tid % 25;
    float bv1 = NEGINF; int bp1 = 0x7fffffff;
    __syncthreads();

    for (int c0 = 0; c0 < cw; c0 += 256) {
        int n = c0 + tid;
        if (n < cw) {
            const float* colp;
            if (n < 125) colp = sup_n + (((size_t)(b * 5 + w)) * 125 + n) * 64;
            else {
                int m = cmp[((size_t)(b * 5 + w)) * 2500 + (n - 125)];
                colp = unl_n + ((size_t)(b * 2500 + m)) * 64;
            }
            float acc[25];
#pragma unroll
            for (int i = 0; i < 25; ++i) acc[i] = 0.f;
#pragma unroll
            for (int cg = 0; cg < 16; ++cg) {
                float4 cv = *(const float4*)(colp + cg * 4);
#pragma unroll
                for (int mq = 0; mq < 25; ++mq) {
                    float4 qv = *(const float4*)&qls[mq * 64 + cg * 4];  // uniform -> broadcast
                    acc[mq] = fmaf(cv.x, qv.x, acc[mq]);
                    acc[mq] = fmaf(cv.y, qv.y, acc[mq]);
                    acc[mq] = fmaf(cv.z, qv.z, acc[mq]);
                    acc[mq] = fmaf(cv.w, qv.w, acc[mq]);
                }
            }
            float cmax = NEGINF; int cam = 0;
#pragma unroll
            for (int mq = 0; mq < 25; ++mq) {
                float s = (acc[mq] + 1.0f) * 0.5f;
                if (s > cmax) { cmax = s; cam = mq; }
                simb[mq * 257 + tid] = s;
            }
            amaxg[(size_t)bq * 3200 + (wb + n)] = (unsigned char)cam;
        }
        __syncthreads();
        if (tid < 200) {
            int base = rg * 32;
            for (int i = 0; i < 32; ++i) {
                int n2 = c0 + base + i;
                if (n2 < cw) {
                    float s = simb[rq * 257 + base + i];
                    if (s > bv1) { bv1 = s; bp1 = ((w * 2625 + n2) << 12) | (wb + n2); }
                }
            }
        }
        __syncthreads();
    }

    if (tid < 200) { redv[rg][rq] = bv1; redp[rg][rq] = bp1; }
    __syncthreads();
    if (tid < 25) {
        float v = redv[0][tid]; int p = redp[0][tid];
#pragma unroll
        for (int g = 1; g < 8; ++g)
            if (redv[g][tid] > v) { v = redv[g][tid]; p = redp[g][tid]; }
        if (L > cntw) {
            int pp = ((w * 2625 + 125 + cntw) << 12) | 0xFFF;
            if (0.5f > v || (0.5f == v && pp < p)) { v = 0.5f; p = pp; }
        }
        size_t o = ((size_t)bq * 5 + w) * 25 + tid;
        bvg[o] = v; bpg[o] = p;
    }
}

// ============================================================
// Kernel CE: merge 5 way-partials per (bq,mq), mutual mask, row loss,
// atomicAdd into d_out. 300 blocks x 64.
// ============================================================
__global__ __launch_bounds__(64) void kce(
    const float* __restrict__ bvg, const int* __restrict__ bpg,
    const unsigned char* __restrict__ amaxg, const int* __restrict__ qy,
    float* __restrict__ out)
{
    int bq = blockIdx.x;
    int tid = threadIdx.x;
    __shared__ float qmask[25];
    __shared__ float lg[5];
    if (tid < 25) {
        float v = NEGINF; int p = 0x7fffffff;
#pragma unroll
        for (int w = 0; w < 5; ++w) {
            size_t o = ((size_t)bq * 5 + w) * 25 + tid;
            float v2 = bvg[o]; int p2 = bpg[o];
            if (v2 > v || (v2 == v && p2 < p)) { v = v2; p = p2; }
        }
        int pos = p & 0xFFF;
        int g = (pos == 0xFFF) ? 0 : (int)amaxg[(size_t)bq * 3200 + pos];
        qmask[tid] = (g == tid) ? 1.0f : 0.0f;
    }
    __syncthreads();
    if (tid < 5) {
        float s = 0.f;
#pragma unroll
        for (int mq = 0; mq < 25; ++mq)
            s += bvg[((size_t)bq * 5 + tid) * 25 + mq] * qmask[mq];
        lg[tid] = s;
    }
    __syncthreads();
    if (tid == 0) {
        int y = qy[bq];
        float mx = lg[0];
#pragma unroll
        for (int w = 1; w < 5; ++w) mx = fmaxf(mx, lg[w]);
        float se = 0.f;
#pragma unroll
        for (int w = 0; w < 5; ++w) se += expf(lg[w] - mx);
        float loss = -(lg[y] - mx - logf(se));
        atomicAdd(out, loss * (1.0f / 300.0f));
    }
}

// ============================================================
extern "C" void kernel_launch(void* const* d_in, const int* in_sizes, int n_in,
                              void* d_out, int out_size, void* d_ws, size_t ws_size,
                              hipStream_t stream)
{
    const float* sup = (const float*)d_in[0];
    const float* qry = (const float*)d_in[2];
    const int*   qy  = (const int*)d_in[3];
    const float* unl = (const float*)d_in[4];

    float* ws    = (float*)d_ws;
    float* unl_n = ws + OF_UNL;
    float* sup_n = ws + OF_SUP;
    float* supT  = ws + OF_SUPT;
    float* qt    = ws + OF_QT;
    float* rowv  = ws + OF_ROWV;
    int*   rowi  = (int*)(ws + OF_ROWI);
    float* colvi = ws + OF_CVI;
    int*   cmp   = (int*)(ws + OF_CMP);
    int*   cntg  = (int*)(ws + OF_CNT);
    int*   unear = (int*)(ws + OF_UNEAR);
    int*   snear = (int*)(ws + OF_SNEAR);
    float* bvg   = ws + OF_BV;
    int*   bpg   = (int*)(ws + OF_BP);
    unsigned char* amaxg = (unsigned char*)(ws + OF_AMX);

    hipMemsetAsync(d_out, 0, sizeof(float), stream);

    hipLaunchKernelGGL(knorm, dim3(1250), dim3(256), 0, stream,
                       sup, qry, unl, unl_n, sup_n, supT, qt);
    hipLaunchKernelGGL(kb, dim3(1600), dim3(256), 0, stream,
                       unl_n, supT, rowv, rowi, colvi);
    hipLaunchKernelGGL(kmerge, dim3(49), dim3(256), 0, stream,
                       rowv, rowi, colvi, unear, snear);
    hipLaunchKernelGGL(kcmp, dim3(20), dim3(256), 0, stream,
                       unear, snear, cmp, cntg);
    hipLaunchKernelGGL(kc1, dim3(1500), dim3(256), 0, stream,
                       qt, sup_n, unl_n, cmp, cntg, bvg, bpg, amaxg);
    hipLaunchKernelGGL(kce, dim3(300), dim3(64), 0, stream,
                       bvg, bpg, amaxg, qy, (float*)d_out);
}